// Round 5
// baseline (145.380 us; speedup 1.0000x reference)
//
#include <hip/hip_runtime.h>
#include <stdint.h>

// Quant3Linear GEMV: y = x @ (scales.T * unpack3(qweight) - zeros.T) + bias
//   x: (1, 8192) f32 | qweight: (768, 28672) i32 | scales,zeros: (28672,1) | bias: (28672,)
// Decomposition per split-K block y over groups [y*GPB, (y+1)*GPB):
//   contribution[o] = scales[o]*acc_y[o] - zeros[o]*S_y  (+ bias[o] iff y==0)
// where S_y = sum of x over that K-range -- zeros term distributes exactly.
// out is zeroed by a memset node; each block atomicAdds its contribution
// (fire-and-forget f32 atomics on a 112 KB L2-resident region).
//
// Single kernel: removes the 3.67 MB partial round-trip + finish dispatch of
// the two-stage version (R2: 143.5 us, R4: 145.3 us).

constexpr int O_FEAT  = 28672;
constexpr int IN_FEAT = 8192;
constexpr int NGROUP  = IN_FEAT / 32;   // 256 groups (3 packed int32 rows each)
constexpr int SPLIT   = 32;             // split-K factor
constexpr int GPB     = NGROUP / SPLIT; // 8 groups per block
constexpr int O4      = O_FEAT / 4;     // uint4 columns per packed row (7168)

typedef uint32_t uint32x4 __attribute__((ext_vector_type(4)));

// Unpack one column-group (32 3-bit codes in w0,w1,w2; GPTQ packing) and
// accumulate dot with xv[0..31]. 3 internal chains cover FMA latency.
__device__ __forceinline__ void dot_group(uint32_t w0, uint32_t w1, uint32_t w2,
                                          const float xv[32], float& acc) {
  float a0 = acc, a1 = 0.f, a2 = 0.f;
  #pragma unroll
  for (int j = 0; j < 10; ++j) a0 += xv[j] * (float)((w0 >> (3 * j)) & 7u);
  a0 += xv[10] * (float)((w0 >> 30) | ((w1 & 1u) << 2));
  #pragma unroll
  for (int j = 0; j < 10; ++j) a1 += xv[11 + j] * (float)((w1 >> (3 * j + 1)) & 7u);
  a1 += xv[21] * (float)((w1 >> 31) | ((w2 & 3u) << 1));
  #pragma unroll
  for (int j = 0; j < 10; ++j) a2 += xv[22 + j] * (float)((w2 >> (3 * j + 2)) & 7u);
  acc = a0 + (a1 + a2);
}

__global__ __launch_bounds__(128) void q3_fused(const float* __restrict__ x,
                                                const uint32x4* __restrict__ qw4,
                                                const float* __restrict__ scales,
                                                const float* __restrict__ zeros,
                                                const float* __restrict__ bias,
                                                float* __restrict__ out) {
  const int tcol4 = blockIdx.x * 128 + threadIdx.x;  // index in units of 4 columns
  const int g0    = blockIdx.y * GPB;
  const uint32x4* qp = qw4 + (size_t)(3 * g0) * O4 + tcol4;
  const float*    xp = x + g0 * 32;                  // block-uniform address

  // S_chunk = sum of x over this block's 256-element K-range (cheap block
  // reduction; needed so the zeros term distributes across split-K blocks).
  float sc = xp[threadIdx.x * 2] + xp[threadIdx.x * 2 + 1];
  #pragma unroll
  for (int off = 32; off > 0; off >>= 1) sc += __shfl_down(sc, off, 64);
  __shared__ float ls[2];
  if ((threadIdx.x & 63) == 0) ls[threadIdx.x >> 6] = sc;
  __syncthreads();
  const float S_chunk = ls[0] + ls[1];

  float acc0 = 0.f, acc1 = 0.f, acc2 = 0.f, acc3 = 0.f;

  // Prologue: first group's weights in flight before the loop.
  uint32x4 wa = qp[0];
  uint32x4 wb = qp[O4];
  uint32x4 wc = qp[2 * O4];

  #pragma unroll
  for (int g = 0; g < GPB; ++g) {
    // Prefetch next group's weights (guard folds away under full unroll).
    uint32x4 na = {0, 0, 0, 0}, nb = {0, 0, 0, 0}, nc = {0, 0, 0, 0};
    qp += 3 * O4;
    if (g < GPB - 1) {
      na = qp[0];
      nb = qp[O4];
      nc = qp[2 * O4];
    }

    float xv[32];
    const float4* x4 = reinterpret_cast<const float4*>(xp);
    #pragma unroll
    for (int u = 0; u < 8; ++u) {
      float4 t = x4[u];
      xv[4 * u + 0] = t.x; xv[4 * u + 1] = t.y;
      xv[4 * u + 2] = t.z; xv[4 * u + 3] = t.w;
    }
    xp += 32;

    dot_group(wa.x, wb.x, wc.x, xv, acc0);  // 4 independent chains
    dot_group(wa.y, wb.y, wc.y, xv, acc1);
    dot_group(wa.z, wb.z, wc.z, xv, acc2);
    dot_group(wa.w, wb.w, wc.w, xv, acc3);

    wa = na; wb = nb; wc = nc;
  }

  // Epilogue: full contribution of this split block, atomically accumulated.
  const float4 sv = reinterpret_cast<const float4*>(scales)[tcol4];
  const float4 zv = reinterpret_cast<const float4*>(zeros)[tcol4];
  float c0 = sv.x * acc0 - zv.x * S_chunk;
  float c1 = sv.y * acc1 - zv.y * S_chunk;
  float c2 = sv.z * acc2 - zv.z * S_chunk;
  float c3 = sv.w * acc3 - zv.w * S_chunk;
  if (blockIdx.y == 0) {  // bias added exactly once
    const float4 bv = reinterpret_cast<const float4*>(bias)[tcol4];
    c0 += bv.x; c1 += bv.y; c2 += bv.z; c3 += bv.w;
  }
  float* op = out + 4 * (size_t)tcol4;
  atomicAdd(op + 0, c0);
  atomicAdd(op + 1, c1);
  atomicAdd(op + 2, c2);
  atomicAdd(op + 3, c3);
}

extern "C" void kernel_launch(void* const* d_in, const int* in_sizes, int n_in,
                              void* d_out, int out_size, void* d_ws, size_t ws_size,
                              hipStream_t stream) {
  const float*    x      = (const float*)d_in[0];
  const uint32x4* qw4    = (const uint32x4*)d_in[1];
  const float*    scales = (const float*)d_in[2];
  const float*    zeros  = (const float*)d_in[3];
  const float*    bias   = (const float*)d_in[4];
  float*          out    = (float*)d_out;

  // out is poisoned 0xAA before every timed call -- zero it (graph-capturable
  // fill node), then accumulate all split-K contributions atomically.
  hipMemsetAsync(out, 0, (size_t)out_size * sizeof(float), stream);
  q3_fused<<<dim3(O4 / 128, SPLIT), dim3(128), 0, stream>>>(x, qw4, scales, zeros,
                                                            bias, out);
}